// Round 2
// 1165.041 us; speedup vs baseline: 1.1659x; 1.1659x over previous
//
#include <hip/hip_runtime.h>

// ---------------------------------------------------------------------------
// Mamba2-style block on MI355X (gfx950).
// R6 = R5 with workspace-overrun fix (NPAD back to 8224; dt GEMM clamps B rows
// via WR instead of padding W_buf).
// Big GEMMs use deep-pipelined schedule (T2+T3+T4+T5):
//   - BK=32, 4-slot LDS ring, prefetch distance 2 K-tiles, counted vmcnt
//   - LDS XOR swizzle cb ^= (row>>1)&3 via pre-swizzled global_load_lds source
//   - 8 waves (512 thr), 16 MFMA/phase, setprio(1) around MFMA clusters
//   - BM=256 for N>=8192 GEMMs, BM=128 for N=2048 GEMMs
//   - gate+up fused into one N=16384 GEMM (interleaved weights, silu in epi)
//   - dt slice split into its own tiny GEMM (main in_proj = clean N=8192)
// ---------------------------------------------------------------------------

typedef unsigned short u16;
typedef __bf16 bf16x8 __attribute__((ext_vector_type(8)));
typedef float f32x4 __attribute__((ext_vector_type(4)));

#define D_MODEL   2048
#define D_INNER   2048
#define NH        32
#define CONV_DIM  6144
#define D_IN_PROJ 8224
#define DFF       8192
#define BATCH     2
#define SEQ       2048
#define M_TOK     4096
#define NCHUNK    16
#define CHUNK     128

__device__ __forceinline__ u16 f2b(float f) {
  union { float f; unsigned int u; } v; v.f = f;
  unsigned int r = v.u + 0x7FFFu + ((v.u >> 16) & 1u);   // RNE
  return (u16)(r >> 16);
}
__device__ __forceinline__ float b2f(u16 u) {
  union { unsigned int u; float f; } v; v.u = ((unsigned int)u) << 16; return v.f;
}

__device__ __forceinline__ void async16(const void* g, void* l) {
  __builtin_amdgcn_global_load_lds((const __attribute__((address_space(1))) void*)g,
                                   (__attribute__((address_space(3))) void*)l, 16, 0, 0);
}

// ---------------------------------------------------------------------------
// NT bf16 GEMM, deep-pipelined: C[M,N] = A[M,K] @ W[N,K]^T.
// Tile BM x 256, BK=32, 4-slot LDS ring, 8 waves (2m x 4n), per-wave BM/2 x 64.
// LDS layout per slot: row-major [rows][32] bf16 with colblk swizzle
//   cb' = cb ^ ((row>>1)&3)   (conflict-free ds_read_b128; rule-21 staging:
//   linear LDS dest + inverse-swizzled per-lane GLOBAL source address).
// Schedule per K-tile: 2 phases (1 for BM=128) of {ds_read, stage-next+2,
//   barrier, lgkmcnt(0), setprio(1), 16 MFMA, setprio(0)}, boundary
//   s_waitcnt vmcnt(LPT) (counted, never 0 in steady state) + barrier.
// WR = valid W rows; B-tile rows >= WR clamp to row 0 (epilogue masks cols).
// EPI 1: Cf = acc + auxf (fp32, may alias)   EPI 4: Cb = bf16(acc)
// EPI 5: Fdt[row*NH+col] = acc (dt slice)    EPI 6: fused silu(gate)*up
// ---------------------------------------------------------------------------
template <int EPI, int BM>
__global__ void __launch_bounds__(512, 2) gemm8(
    const u16* __restrict__ A, const u16* __restrict__ W,
    float* Cf, u16* Cb, const float* __restrict__ auxf, float* Fdt,
    int K, int Nbound, int ldC, int GN, int WR) {
  constexpr int RB = BM / 32;          // rowblocks per wave (8 or 4)
  constexpr int CA = BM / 128;         // A chunk-loads / thread / tile (2 or 1)
  constexpr int LPT = CA + 2;          // loads / thread / tile
  constexpr int SLOT_A = BM * 32;      // u16 per ring slot
  constexpr int SLOT_B = 256 * 32;
  __shared__ __align__(16) u16 sA[4 * SLOT_A];
  __shared__ __align__(16) u16 sB[4 * SLOT_B];

  const int tid = threadIdx.x;
  const int lane = tid & 63, wave = tid >> 6;

  // bijective XCD chunk swizzle (m204)
  const int nwg = gridDim.x;
  const int q = nwg >> 3, r = nwg & 7, xc = blockIdx.x & 7, jj = blockIdx.x >> 3;
  const int wg = (xc < r ? xc * (q + 1) : r * (q + 1) + (xc - r) * q) + jj;
  const int bm = wg / GN, bn = wg % GN;

  const int wrow = (wave >> 2) * (BM / 2);
  const int wcol = (wave & 3) * 64;

  // staging: chunk = 1KB = 16 rows x 64B; lane l -> row l>>2, dest colblk l&3,
  // source colblk = (l&3) ^ ((l>>3)&3)  (inverse of read swizzle)
  const int l2 = lane >> 2;
  const int cbl = (lane & 3) ^ ((lane >> 3) & 3);
  const u16* pa[CA];
  const u16* pb[2];
#pragma unroll
  for (int i = 0; i < CA; ++i)
    pa[i] = A + (size_t)(bm * BM + (wave * CA + i) * 16 + l2) * K + cbl * 8;
#pragma unroll
  for (int i = 0; i < 2; ++i) {
    int br = bn * 256 + (wave * 2 + i) * 16 + l2;
    if (br >= WR) br = 0;              // in-bounds garbage; epilogue masks cols
    pb[i] = W + (size_t)br * K + cbl * 8;
  }

  auto stageA = [&](int slot) {
#pragma unroll
    for (int i = 0; i < CA; ++i) {
      async16(pa[i], &sA[slot * SLOT_A + (wave * CA + i) * 512 + lane * 8]);
      pa[i] += 32;
    }
  };
  auto stageB = [&](int slot) {
#pragma unroll
    for (int i = 0; i < 2; ++i) {
      async16(pb[i], &sB[slot * SLOT_B + (wave * 2 + i) * 512 + lane * 8]);
      pb[i] += 32;
    }
  };

  // swizzled per-lane read offset (u16): row=lr, colblk=(lane>>4)^((lr>>1)&3)
  const int lr = lane & 15;
  const int afo = lr * 32 + ((((lane >> 4) ^ ((lr >> 1) & 3))) << 3);

  f32x4 acc[RB][4];
  const f32x4 z4 = {0.f, 0.f, 0.f, 0.f};
#pragma unroll
  for (int m = 0; m < RB; ++m)
#pragma unroll
    for (int n = 0; n < 4; ++n) acc[m][n] = z4;

  const int NT = K >> 5;
  stageA(0); stageB(0);
  stageA(1); stageB(1);
  asm volatile("s_waitcnt vmcnt(%0)" :: "n"(LPT) : "memory");
  __builtin_amdgcn_s_barrier();
  __builtin_amdgcn_sched_barrier(0);

  for (int t = 0; t < NT; ++t) {
    const int slot = t & 3;
    const int s2 = (t + 2) & 3;
    const bool pf = (t + 2 < NT);
    const u16* sAs = &sA[slot * SLOT_A + wrow * 32 + afo];
    const u16* sBs = &sB[slot * SLOT_B + wcol * 32 + afo];
    bf16x8 av[4], bv[4];
    // ---- phase 0: rowblocks 0..3 x all 4 colblocks ----
#pragma unroll
    for (int m = 0; m < 4; ++m) av[m] = *(const bf16x8*)(sAs + m * 512);
#pragma unroll
    for (int n = 0; n < 4; ++n) bv[n] = *(const bf16x8*)(sBs + n * 512);
    if (pf) stageA(s2);
    if constexpr (RB == 4) { if (pf) stageB(s2); }
    __builtin_amdgcn_s_barrier();
    asm volatile("s_waitcnt lgkmcnt(0)" ::: "memory");
    __builtin_amdgcn_sched_barrier(0);
    __builtin_amdgcn_s_setprio(1);
#pragma unroll
    for (int m = 0; m < 4; ++m)
#pragma unroll
      for (int n = 0; n < 4; ++n)
        acc[m][n] = __builtin_amdgcn_mfma_f32_16x16x32_bf16(av[m], bv[n], acc[m][n], 0, 0, 0);
    __builtin_amdgcn_s_setprio(0);
    if constexpr (RB == 8) {
      __builtin_amdgcn_s_barrier();
      __builtin_amdgcn_sched_barrier(0);
      // ---- phase 1: rowblocks 4..7, reuse bv ----
#pragma unroll
      for (int m = 0; m < 4; ++m) av[m] = *(const bf16x8*)(sAs + (m + 4) * 512);
      if (pf) stageB(s2);
      __builtin_amdgcn_s_barrier();
      asm volatile("s_waitcnt lgkmcnt(0)" ::: "memory");
      __builtin_amdgcn_sched_barrier(0);
      __builtin_amdgcn_s_setprio(1);
#pragma unroll
      for (int m = 0; m < 4; ++m)
#pragma unroll
        for (int n = 0; n < 4; ++n)
          acc[m + 4][n] = __builtin_amdgcn_mfma_f32_16x16x32_bf16(av[m], bv[n], acc[m + 4][n], 0, 0, 0);
      __builtin_amdgcn_s_setprio(0);
    }
    // boundary: retire tile t+1's loads, keep tile t+2's in flight
    if (pf) { asm volatile("s_waitcnt vmcnt(%0)" :: "n"(LPT) : "memory"); }
    else    { asm volatile("s_waitcnt vmcnt(0)" ::: "memory"); }
    __builtin_amdgcn_s_barrier();
    __builtin_amdgcn_sched_barrier(0);
  }

  // ---- epilogue ----  C/D: row=(lane>>4)*4+reg, col=lane&15
  const int er = (lane >> 4) * 4, ec = lane & 15;
  const int bmb = bm * BM + wrow, bnb = bn * 256 + wcol;
  if constexpr (EPI == 6) {
#pragma unroll
    for (int m = 0; m < RB; ++m)
#pragma unroll
      for (int rr = 0; rr < 4; ++rr) {
        const size_t grow = bmb + m * 16 + er + rr;
#pragma unroll
        for (int n = 0; n < 4; n += 2) {
          const int oc = ((bnb + n * 16) >> 5) * 16 + ec;
          const float g = acc[m][n][rr], u = acc[m][n + 1][rr];
          const float sg = 1.f / (1.f + __expf(-g));
          Cb[grow * DFF + oc] = f2b(u * g * sg);
        }
      }
  } else {
#pragma unroll
    for (int m = 0; m < RB; ++m)
#pragma unroll
      for (int rr = 0; rr < 4; ++rr) {
        const int grow = bmb + m * 16 + er + rr;
#pragma unroll
        for (int n = 0; n < 4; ++n) {
          const int gcol = bnb + n * 16 + ec;
          if (gcol < Nbound) {
            const float v = acc[m][n][rr];
            if constexpr (EPI == 1) {
              const size_t idx = (size_t)grow * ldC + gcol;
              Cf[idx] = v + auxf[idx];
            } else if constexpr (EPI == 4) {
              Cb[(size_t)grow * ldC + gcol] = f2b(v);
            } else if constexpr (EPI == 5) {
              Fdt[(size_t)grow * NH + gcol] = v;
            }
          }
        }
      }
  }
}

// ---------------------------------------------------------------------------
__global__ void cvt_kernel(const float* __restrict__ s, u16* __restrict__ d, int n4) {
  const int i = blockIdx.x * 256 + threadIdx.x;
  if (i >= n4) return;
  const float4 v = ((const float4*)s)[i];
  ushort4 r;
  r.x = f2b(v.x); r.y = f2b(v.y); r.z = f2b(v.z); r.w = f2b(v.w);
  ((ushort4*)d)[i] = r;
}

// gate/up weights -> bf16, 16-row interleaved: virtual rows [g*32, g*32+16) =
// gate rows [g*16, g*16+16), [g*32+16, g*32+32) = up rows (for fused EPI 6).
__global__ void cvt_gateup_kernel(const float* __restrict__ g, const float* __restrict__ u,
                                  u16* __restrict__ d) {
  const int i = blockIdx.x * 256 + threadIdx.x;
  const int total = 2 * DFF * D_MODEL / 4;
  if (i >= total) return;
  const int rowlen4 = D_MODEL / 4;
  const int vrow = i / rowlen4, c4 = i % rowlen4;
  const bool isg = vrow < DFF;
  const int sr = isg ? vrow : vrow - DFF;
  const float4 v = ((const float4*)(isg ? g : u))[(size_t)sr * rowlen4 + c4];
  const int dr = (sr >> 4) * 32 + (isg ? 0 : 16) + (sr & 15);
  ushort4 rr; rr.x = f2b(v.x); rr.y = f2b(v.y); rr.z = f2b(v.z); rr.w = f2b(v.w);
  ((ushort4*)d)[(size_t)dr * rowlen4 + c4] = rr;
}

__global__ void rmsnorm_kernel(const float* __restrict__ x, const float* __restrict__ w,
                               u16* __restrict__ o) {
  const int row = blockIdx.x;
  const float* xr = x + (size_t)row * D_MODEL;
  float ss = 0.f;
  for (int c = threadIdx.x; c < D_MODEL; c += 256) { const float v = xr[c]; ss += v * v; }
#pragma unroll
  for (int off = 32; off > 0; off >>= 1) ss += __shfl_down(ss, off, 64);
  __shared__ float red[4];
  if ((threadIdx.x & 63) == 0) red[threadIdx.x >> 6] = ss;
  __syncthreads();
  const float scale = rsqrtf((red[0] + red[1] + red[2] + red[3]) * (1.f / D_MODEL) + 1e-5f);
  u16* orow = o + (size_t)row * D_MODEL;
  for (int c = threadIdx.x; c < D_MODEL; c += 256) orow[c] = f2b(xr[c] * scale * w[c]);
}

// causal depthwise conv over seq dim; reads xBC slice of bf16 zxbcdt.
__global__ void conv_kernel(const u16* __restrict__ zx, const float* __restrict__ cw,
                            const float* __restrict__ cb, u16* __restrict__ out) {
  const int idx = blockIdx.x * 256 + threadIdx.x;   // M_TOK * CONV_DIM
  const int ch = idx % CONV_DIM;
  const int m = idx / CONV_DIM;
  const int l = m & (SEQ - 1);
  float accv = cb[ch];
#pragma unroll
  for (int k = 0; k < 4; ++k) {
    const int ls = l - 3 + k;
    if (ls >= 0) accv += cw[ch * 4 + k] * b2f(zx[(size_t)(m - 3 + k) * D_IN_PROJ + D_INNER + ch]);
  }
  out[idx] = f2b(accv);
}

// per (b,chunk,head): cum[i] = sum_{i'<=i} -softplus(dt)   (dt fp32 side buf)
__global__ void dtcum_kernel(const float* __restrict__ dtbuf, float* __restrict__ cum) {
  const int blk = blockIdx.x;                       // b*512 + c*32 + h
  const int h = blk & 31, cc = (blk >> 5) & 15, b = blk >> 9;
  const int i = threadIdx.x;                        // 0..127
  const int m = b * SEQ + cc * CHUNK + i;
  const float dt = dtbuf[(size_t)m * NH + h];
  const float sp = (dt > 20.f) ? dt : log1pf(__expf(dt));
  __shared__ float s[128];
  s[i] = -sp;
  __syncthreads();
  for (int off = 1; off < 128; off <<= 1) {
    const float v = (i >= off) ? s[i - off] : 0.f;
    __syncthreads();
    s[i] += v;
    __syncthreads();
  }
  cum[(size_t)m * NH + h] = s[i];
}

// per (b,chunk,head): S[n][p] = sum_q exp(cum_last - cum_q) * B[q][n] * x[q][p]
__global__ void state_kernel(const u16* __restrict__ xbc, const float* __restrict__ cum,
                             float* __restrict__ S) {
  const int blk = blockIdx.x;
  const int h = blk & 31, cc = (blk >> 5) & 15, b = blk >> 9;
  const int m0 = b * SEQ + cc * CHUNK;
  const int tid = threadIdx.x;
  const int tp = tid & 63, tg = tid >> 6;
  const int n0 = tg * 16;
  const float cl = cum[(size_t)(m0 + 127) * NH + h];
  __shared__ float sBq[32][64], sxq[32][64], sd[32];
  float accv[16];
#pragma unroll
  for (int i = 0; i < 16; ++i) accv[i] = 0.f;
  for (int q0 = 0; q0 < 128; q0 += 32) {
    __syncthreads();
    for (int e = tid; e < 2048; e += 256) {
      const int q = e >> 6, col = e & 63;
      const size_t rowb = (size_t)(m0 + q0 + q) * CONV_DIM;
      sBq[q][col] = b2f(xbc[rowb + D_INNER + h * 64 + col]);
      sxq[q][col] = b2f(xbc[rowb + h * 64 + col]);
    }
    if (tid < 32) sd[tid] = __expf(cl - cum[(size_t)(m0 + q0 + tid) * NH + h]);
    __syncthreads();
    for (int q = 0; q < 32; ++q) {
      const float xv = sxq[q][tp] * sd[q];
#pragma unroll
      for (int i = 0; i < 16; ++i) accv[i] += sBq[q][n0 + i] * xv;
    }
  }
  float* Sp = S + (((size_t)(b * 16 + cc) * NH + h) * 64) * 64;
#pragma unroll
  for (int i = 0; i < 16; ++i) Sp[(size_t)(n0 + i) * 64 + tp] = accv[i];
}

// inter-chunk scan: Hprev[c] = state before chunk c (16 sequential steps)
__global__ void scan_kernel(const float* __restrict__ S, const float* __restrict__ cum,
                            float* __restrict__ H) {
  const int idx = blockIdx.x * 256 + threadIdx.x;   // BATCH*NH*64*64
  const int p = idx & 63, n = (idx >> 6) & 63, h = (idx >> 12) & 31, b = idx >> 17;
  float hs = 0.f;
  for (int cc = 0; cc < NCHUNK; ++cc) {
    const size_t off = (((size_t)(b * 16 + cc) * NH + h) * 64 + n) * 64 + p;
    H[off] = hs;
    const float Ac = __expf(cum[(size_t)(b * SEQ + cc * CHUNK + 127) * NH + h]);
    hs = Ac * hs + S[off];
  }
}

// ---------------------------------------------------------------------------
// y_kernel (MFMA): one block per (b, chunk, head).
// Phase 1: P = mask(exp(cum_i-cum_j) * C·B^T)  [MFMA, bf16 P in LDS]
// Phase 2: Y = P·x + (exp(cum)·C)·H            [MFMA], then +D*x, z-silu gate.
// LDS strides padded (+8 u16) -> 2-way bank aliasing only (free).
// ---------------------------------------------------------------------------
#define SPITCH 136   // sP / sxT row pitch (u16)
#define CPITCH 72    // sC / sB / sHT row pitch (u16)
__global__ void __launch_bounds__(256, 2) y_kernel(
    const u16* __restrict__ xbc, const float* __restrict__ cum,
    const float* __restrict__ H, const float* __restrict__ Dp,
    const u16* __restrict__ zx, const float* __restrict__ zb,
    u16* __restrict__ yo) {
  const int blk = blockIdx.x;            // b*512 + cc*32 + h
  const int h = blk & 31, cc = (blk >> 5) & 15, b = blk >> 9;
  const int m0 = b * SEQ + cc * CHUNK;
  const int tid = threadIdx.x;
  const int lane = tid & 63, wave = tid >> 6;

  __shared__ __align__(16) u16 sC[128 * CPITCH];          // 18 KB  C[i][n] (later exp-scaled)
  __shared__ __align__(16) u16 sU[64 * SPITCH + 64 * CPITCH]; // 26 KB  ph1: sB[j][n]; ph2: sxT[p][j] + sHT[p][n]
  __shared__ __align__(16) u16 sP[128 * SPITCH];          // 34 KB  P[i][j] bf16
  __shared__ float sCum[128];
  u16* sB = sU;
  u16* sxT = sU;
  u16* sHT = sU + 64 * SPITCH;

  // ---- load C, B, cum ----
  {
    const int i = tid >> 4, n4 = (tid & 15) * 4;          // 8 rows/iter, ushort4
    for (int i0 = 0; i0 < 128; i0 += 16) {
      const size_t g = (size_t)(m0 + i0 + i) * CONV_DIM + h * 64 + n4;
      *(ushort4*)&sC[(i0 + i) * CPITCH + n4] = *(const ushort4*)&xbc[g + 2 * D_INNER];
      *(ushort4*)&sB[(i0 + i) * CPITCH + n4] = *(const ushort4*)&xbc[g + D_INNER];
    }
    if (tid < 128) sCum[tid] = cum[(size_t)(m0 + tid) * NH + h];
  }
  __syncthreads();

  const int lr = lane & 15;
  const int lk = (lane >> 4) * 8;
  const int er = (lane >> 4) * 4;
  const int ec = lane & 15;

  // ---- phase 1: scores ----
  {
    const int R = (wave >> 1) * 64, Cq = (wave & 1) * 64;
    const f32x4 z4 = {0.f, 0.f, 0.f, 0.f};
    f32x4 acc[4][4];
#pragma unroll
    for (int i = 0; i < 4; ++i)
#pragma unroll
      for (int j = 0; j < 4; ++j) acc[i][j] = z4;
#pragma unroll
    for (int k0 = 0; k0 < 64; k0 += 32) {
      bf16x8 af[4], bfv[4];
#pragma unroll
      for (int mi = 0; mi < 4; ++mi)
        af[mi] = *(const bf16x8*)&sC[(R + mi * 16 + lr) * CPITCH + k0 + lk];
#pragma unroll
      for (int ni = 0; ni < 4; ++ni)
        bfv[ni] = *(const bf16x8*)&sB[(Cq + ni * 16 + lr) * CPITCH + k0 + lk];
#pragma unroll
      for (int mi = 0; mi < 4; ++mi)
#pragma unroll
        for (int ni = 0; ni < 4; ++ni)
          acc[mi][ni] = __builtin_amdgcn_mfma_f32_16x16x32_bf16(af[mi], bfv[ni], acc[mi][ni], 0, 0, 0);
    }
#pragma unroll
    for (int mi = 0; mi < 4; ++mi)
#pragma unroll
      for (int r = 0; r < 4; ++r) {
        const int row = R + mi * 16 + er + r;
#pragma unroll
        for (int ni = 0; ni < 4; ++ni) {
          const int col = Cq + ni * 16 + ec;
          const float pv = (row >= col) ? __expf(sCum[row] - sCum[col]) * acc[mi][ni][r] : 0.f;
          sP[row * SPITCH + col] = f2b(pv);
        }
      }
  }
  __syncthreads();

  // ---- phase 1.5: scale C rows by exp(cum); load x^T, H^T (overwrite sB) ----
  {
    const int i = tid >> 1, n32 = (tid & 1) * 32;         // sC scale: 128 rows x 64
    const float sc = __expf(sCum[i]);
    for (int n = n32; n < n32 + 32; ++n)
      sC[i * CPITCH + n] = f2b(b2f(sC[i * CPITCH + n]) * sc);
  }
  {
    const int j = tid >> 1, p32 = (tid & 1) * 32;         // x[j][p] -> sxT[p][j]
    const size_t g = (size_t)(m0 + j) * CONV_DIM + h * 64;
    for (int p = p32; p < p32 + 32; ++p)
      sxT[p * SPITCH + j] = xbc[g + p];
    const float* Hp = H + (((size_t)(b * 16 + cc) * NH + h) * 64) * 64;
    if (j < 64) {                                          // H[n][p] -> sHT[p][n]
      const int n = j;
      for (int p = p32; p < p32 + 32; ++p)
        sHT[p * CPITCH + n] = f2b(Hp[n * 64 + p]);
    }
  }
  __syncthreads();

  // ---- phase 2: Y = P·x + Cs·H ----
  {
    const int R2 = wave * 32;
    const f32x4 z4 = {0.f, 0.f, 0.f, 0.f};
    f32x4 acc[2][4];
#pragma unroll
    for (int i = 0; i < 2; ++i)
#pragma unroll
      for (int j = 0; j < 4; ++j) acc[i][j] = z4;
#pragma unroll
    for (int k0 = 0; k0 < 128; k0 += 32) {                 // P·x
      bf16x8 af[2], bfv[4];
#pragma unroll
      for (int mi = 0; mi < 2; ++mi)
        af[mi] = *(const bf16x8*)&sP[(R2 + mi * 16 + lr) * SPITCH + k0 + lk];
#pragma unroll
      for (int ni = 0; ni < 4; ++ni)
        bfv[ni] = *(const bf16x8*)&sxT[(ni * 16 + lr) * SPITCH + k0 + lk];
#pragma unroll
      for (int mi = 0; mi < 2; ++mi)
#pragma unroll
        for (int ni = 0; ni < 4; ++ni)
          acc[mi][ni] = __builtin_amdgcn_mfma_f32_16x16x32_bf16(af[mi], bfv[ni], acc[mi][ni], 0, 0, 0);
    }
#pragma unroll
    for (int k0 = 0; k0 < 64; k0 += 32) {                  // Cs·H
      bf16x8 af[2], bfv[4];
#pragma unroll
      for (int mi = 0; mi < 2; ++mi)
        af[mi] = *(const bf16x8*)&sC[(R2 + mi * 16 + lr) * CPITCH + k0 + lk];
#pragma unroll
      for (int ni = 0; ni < 4; ++ni)
        bfv[ni] = *(const bf16x8*)&sHT[(ni * 16 + lr) * CPITCH + k0 + lk];
#pragma unroll
      for (int mi = 0; mi < 2; ++mi)
#pragma unroll
        for (int ni = 0; ni < 4; ++ni)
          acc[mi][ni] = __builtin_amdgcn_mfma_f32_16x16x32_bf16(af[mi], bfv[ni], acc[mi][ni], 0, 0, 0);
    }
    // epilogue: += D*x, z-silu gate, bf16 store
    const float Dh = Dp[h];
#pragma unroll
    for (int mi = 0; mi < 2; ++mi)
#pragma unroll
      for (int r = 0; r < 4; ++r) {
        const int row = R2 + mi * 16 + er + r;
        const int m = m0 + row;
#pragma unroll
        for (int ni = 0; ni < 4; ++ni) {
          const int p = ni * 16 + ec;
          const int gc = h * 64 + p;
          const float xv = b2f(sxT[p * SPITCH + row]);
          const float z = b2f(zx[(size_t)m * D_IN_PROJ + gc]) + zb[gc];
          const float sg = 1.f / (1.f + __expf(-z));
          yo[(size_t)m * D_INNER + gc] = f2b((acc[mi][ni][r] + Dh * xv) * z * sg);
        }
      }
  }
}

// ---------------------------------------------------------------------------
extern "C" void kernel_launch(void* const* d_in, const int* in_sizes, int n_in,
                              void* d_out, int out_size, void* d_ws, size_t ws_size,
                              hipStream_t stream) {
  (void)in_sizes; (void)n_in; (void)out_size; (void)ws_size;
  const float* hidden = (const float*)d_in[0];
  const float* w_in   = (const float*)d_in[1];
  const float* z_bias = (const float*)d_in[2];
  const float* conv_w = (const float*)d_in[3];
  const float* conv_b = (const float*)d_in[4];
  const float* Dp     = (const float*)d_in[5];
  const float* w_out  = (const float*)d_in[6];
  const float* n1w    = (const float*)d_in[7];
  const float* n2w    = (const float*)d_in[8];
  const float* w_g    = (const float*)d_in[9];
  const float* w_u    = (const float*)d_in[10];
  const float* w_d    = (const float*)d_in[11];
  float* out = (float*)d_out;

  // ---- workspace layout (~193.4 MiB total, <= prior session's footprint) ----
  char* p = (char*)d_ws;
  auto take = [&](size_t bytes) { char* r = p; p += (bytes + 255) & ~(size_t)255; return r; };
  u16*   Bzx  = (u16*)take((size_t)M_TOK * D_IN_PROJ * 2);              // 64.25 MiB
  u16*   Bxbc = (u16*)take((size_t)M_TOK * CONV_DIM * 2);               // 48 MiB
  float* F_cum = (float*)take((size_t)M_TOK * NH * 4);                  // 0.5 MiB
  float* F_S   = (float*)take((size_t)BATCH * NCHUNK * NH * 64 * 64 * 4); // 16 MiB
  float* F_H   = (float*)take((size_t)BATCH * NCHUNK * NH * 64 * 64 * 4); // 16 MiB
  u16*   B_h   = (u16*)take((size_t)M_TOK * D_MODEL * 2);               // 16 MiB
  float* F_dt  = (float*)take((size_t)M_TOK * NH * 4);                  // 0.5 MiB
  u16*   W_buf = (u16*)take((size_t)D_IN_PROJ * D_MODEL * 2);           // 32.125 MiB
  // overlays (liveness-checked):
  u16* B_y  = (u16*)F_S;    // y-gated output (16 MiB): F_S dead after scan_kernel
  u16* W_gu = Bzx;          // fused gate/up weights (64 MiB): Bzx dead after y_kernel
  u16* B_gu = Bxbc;         // gated-up out (64 MiB): spans Bxbc+F_cum+F_S, all dead
                            // by then (out_proj consumed B_y before gate-up runs)

  const int c2 = (D_MODEL * D_INNER / 4 + 255) / 256;
  const int c8 = (DFF * D_MODEL / 4 + 255) / 256;

  // 1. in_proj: convert weight, norm, main GEMM (N=8192 exact) + dt GEMM (N=32)
  cvt_kernel<<<(D_IN_PROJ * D_MODEL / 4 + 255) / 256, 256, 0, stream>>>(w_in, W_buf, D_IN_PROJ * D_MODEL / 4);
  rmsnorm_kernel<<<M_TOK, 256, 0, stream>>>(hidden, n1w, B_h);
  gemm8<4, 256><<<16 * 32, 512, 0, stream>>>(B_h, W_buf, nullptr, Bzx, nullptr, nullptr,
                                             D_MODEL, 8192, D_IN_PROJ, 32, 8192);
  gemm8<5, 128><<<32, 512, 0, stream>>>(B_h, W_buf + (size_t)8192 * D_MODEL, nullptr, nullptr,
                                        nullptr, F_dt, D_MODEL, NH, 0, 1, 32);

  // 2. conv + SSD scan
  conv_kernel<<<M_TOK * CONV_DIM / 256, 256, 0, stream>>>(Bzx, conv_w, conv_b, Bxbc);
  dtcum_kernel<<<BATCH * NCHUNK * NH, 128, 0, stream>>>(F_dt, F_cum);
  state_kernel<<<BATCH * NCHUNK * NH, 256, 0, stream>>>(Bxbc, F_cum, F_S);
  scan_kernel<<<BATCH * NH * 64 * 64 / 256, 256, 0, stream>>>(F_S, F_cum, F_H);
  y_kernel<<<BATCH * NCHUNK * NH, 256, 0, stream>>>(Bxbc, F_cum, F_H, Dp, Bzx, z_bias, B_y);

  // 3. out_proj (+residual) -> d_out
  cvt_kernel<<<c2, 256, 0, stream>>>(w_out, W_buf, D_MODEL * D_INNER / 4);
  gemm8<1, 128><<<32 * 8, 512, 0, stream>>>(B_y, W_buf, out, nullptr, hidden, nullptr,
                                            D_INNER, D_MODEL, D_MODEL, 8, 2048);

  // 4. MLP: norm2, fused gate-up GEMM (N=16384, interleaved W), down (+residual)
  rmsnorm_kernel<<<M_TOK, 256, 0, stream>>>(out, n2w, B_h);
  cvt_gateup_kernel<<<2 * DFF * D_MODEL / 4 / 256, 256, 0, stream>>>(w_g, w_u, W_gu);
  gemm8<6, 256><<<16 * 64, 512, 0, stream>>>(B_h, W_gu, nullptr, B_gu, nullptr, nullptr,
                                             D_MODEL, 2 * DFF, 0, 64, 16384);
  cvt_kernel<<<c8, 256, 0, stream>>>(w_d, W_buf, D_MODEL * DFF / 4);
  gemm8<1, 128><<<32 * 8, 512, 0, stream>>>(B_gu, W_buf, out, nullptr, out,
                                            nullptr, DFF, D_MODEL, D_MODEL, 8, 2048);
}

// Round 3
// 1091.669 us; speedup vs baseline: 1.2443x; 1.0672x over previous
//
#include <hip/hip_runtime.h>

// ---------------------------------------------------------------------------
// Mamba2-style block on MI355X (gfx950).
// R7: overlap ds_read with MFMA via tile-granularity register pipeline:
//   - prefetch distance 3, 4 SEPARATE __shared__ slot arrays (no alias waits)
//   - per K-tile: issue next-tile frag reads + stage t+3, then 32 MFMA;
//     compiler inserts counted lgkmcnt from reg deps (reads hide under MFMA)
//   - ONE barrier + counted vmcnt per K-tile (was 4 barriers + lgkmcnt(0))
//   - GM=4 bm-grouping inside XCD chunk (L2 working set 33 -> 12 MiB)
// Carried from R6: LDS XOR swizzle (bank-conflict 0), 8 waves, setprio,
//   fused gate-up GEMM, dt split, BM=256 (N>=8192) / BM=128 (N=2048).
// ---------------------------------------------------------------------------

typedef unsigned short u16;
typedef __bf16 bf16x8 __attribute__((ext_vector_type(8)));
typedef float f32x4 __attribute__((ext_vector_type(4)));

#define D_MODEL   2048
#define D_INNER   2048
#define NH        32
#define CONV_DIM  6144
#define D_IN_PROJ 8224
#define DFF       8192
#define BATCH     2
#define SEQ       2048
#define M_TOK     4096
#define NCHUNK    16
#define CHUNK     128

__device__ __forceinline__ u16 f2b(float f) {
  union { float f; unsigned int u; } v; v.f = f;
  unsigned int r = v.u + 0x7FFFu + ((v.u >> 16) & 1u);   // RNE
  return (u16)(r >> 16);
}
__device__ __forceinline__ float b2f(u16 u) {
  union { unsigned int u; float f; } v; v.u = ((unsigned int)u) << 16; return v.f;
}

__device__ __forceinline__ void async16(const void* g, void* l) {
  __builtin_amdgcn_global_load_lds((const __attribute__((address_space(1))) void*)g,
                                   (__attribute__((address_space(3))) void*)l, 16, 0, 0);
}

// ---------------------------------------------------------------------------
// NT bf16 GEMM, pipelined: C[M,N] = A[M,K] @ W[N,K]^T.  Tile BM x 256, BK=32.
// 4 separate LDS slot arrays (ring), prefetch distance 3.  8 waves (2m x 4n),
// per-wave BM/2 x 64.  Per-slot layout: row-major [rows][32] bf16, colblk
// swizzle cb' = cb ^ ((row>>1)&3); staged with linear LDS dest + inverse-
// swizzled per-lane GLOBAL source (rule 21).  Conflict-free (R6: BANK_CONF=0).
// Steady-state K-tile t: {issue 12 ds_reads (tile t+1, slot t+1) | stage tile
// t+3 | 32 MFMA on tile-t regs} -> vmcnt(LPT) -> s_barrier.  Compiler emits
// counted lgkmcnt from reg deps, so reads/stages overlap MFMA.
// WR = valid W rows; B-tile rows >= WR clamp to row 0 (epilogue masks cols).
// EPI 1: Cf = acc + auxf (fp32, may alias)   EPI 4: Cb = bf16(acc)
// EPI 5: Fdt[row*NH+col] = acc (dt slice)    EPI 6: fused silu(gate)*up
// ---------------------------------------------------------------------------
template <int EPI, int BM>
__global__ void __launch_bounds__(512, 2) gemm8(
    const u16* __restrict__ A, const u16* __restrict__ W,
    float* Cf, u16* Cb, const float* __restrict__ auxf, float* Fdt,
    int K, int Nbound, int ldC, int GN, int WR) {
  constexpr int RB = BM / 32;          // rowblocks per wave (8 or 4)
  constexpr int CA = BM / 128;         // A chunk-loads / thread / tile (2 or 1)
  constexpr int LPT = CA + 2;          // loads / thread / tile
  constexpr int SLOT_A = BM * 32;      // u16 per ring slot
  constexpr int SLOT_B = 256 * 32;
  __shared__ __align__(16) u16 sA0[SLOT_A], sA1[SLOT_A], sA2[SLOT_A], sA3[SLOT_A];
  __shared__ __align__(16) u16 sB0[SLOT_B], sB1[SLOT_B], sB2[SLOT_B], sB3[SLOT_B];
  u16* const slA[4] = {sA0, sA1, sA2, sA3};
  u16* const slB[4] = {sB0, sB1, sB2, sB3};

  const int tid = threadIdx.x;
  const int lane = tid & 63, wave = tid >> 6;

  // bijective XCD chunk swizzle (m204) + GM=4 bm-grouping inside chunk
  const int nwg = gridDim.x;
  const int q = nwg >> 3, r = nwg & 7, xc = blockIdx.x & 7, jj = blockIdx.x >> 3;
  const int wg = (xc < r ? xc * (q + 1) : r * (q + 1) + (xc - r) * q) + jj;
  const int gm = wg / (4 * GN), rm = wg % (4 * GN);
  const int bm = gm * 4 + (rm & 3), bn = rm >> 2;

  const int wrow = (wave >> 2) * (BM / 2);
  const int wcol = (wave & 3) * 64;

  // staging: chunk = 1KB = 16 rows x 64B; lane l -> row l>>2, dest colblk l&3,
  // source colblk = (l&3) ^ ((l>>3)&3)  (inverse of read swizzle)
  const int l2 = lane >> 2;
  const int cbl = (lane & 3) ^ ((lane >> 3) & 3);
  const u16* pa[CA];
  const u16* pb[2];
#pragma unroll
  for (int i = 0; i < CA; ++i)
    pa[i] = A + (size_t)(bm * BM + (wave * CA + i) * 16 + l2) * K + cbl * 8;
#pragma unroll
  for (int i = 0; i < 2; ++i) {
    int br = bn * 256 + (wave * 2 + i) * 16 + l2;
    if (br >= WR) br = 0;              // in-bounds garbage; epilogue masks cols
    pb[i] = W + (size_t)br * K + cbl * 8;
  }

  auto stageAB = [&](u16* sa, u16* sb) {
#pragma unroll
    for (int i = 0; i < CA; ++i) {
      async16(pa[i], sa + (wave * CA + i) * 512 + lane * 8);
      pa[i] += 32;
    }
#pragma unroll
    for (int i = 0; i < 2; ++i) {
      async16(pb[i], sb + (wave * 2 + i) * 512 + lane * 8);
      pb[i] += 32;
    }
  };

  // swizzled per-lane read offset (u16): row=lr, colblk=(lane>>4)^((lr>>1)&3)
  const int lr = lane & 15;
  const int afo = lr * 32 + ((((lane >> 4) ^ ((lr >> 1) & 3))) << 3);

  auto rdFrags = [&](const u16* sa, const u16* sb, bf16x8 (&fa)[RB], bf16x8 (&fb)[4]) {
    const u16* ap = sa + wrow * 32 + afo;
    const u16* bp = sb + wcol * 32 + afo;
#pragma unroll
    for (int m = 0; m < RB; ++m) fa[m] = *(const bf16x8*)(ap + m * 512);
#pragma unroll
    for (int n = 0; n < 4; ++n) fb[n] = *(const bf16x8*)(bp + n * 512);
  };

  f32x4 acc[RB][4];
  const f32x4 z4 = {0.f, 0.f, 0.f, 0.f};
#pragma unroll
  for (int m = 0; m < RB; ++m)
#pragma unroll
    for (int n = 0; n < 4; ++n) acc[m][n] = z4;

  auto doMFMA = [&](bf16x8 (&fa)[RB], bf16x8 (&fb)[4]) {
    __builtin_amdgcn_s_setprio(1);
#pragma unroll
    for (int m = 0; m < RB; ++m)
#pragma unroll
      for (int n = 0; n < 4; ++n)
        acc[m][n] = __builtin_amdgcn_mfma_f32_16x16x32_bf16(fa[m], fb[n], acc[m][n], 0, 0, 0);
    __builtin_amdgcn_s_setprio(0);
  };

#define BOUNDARY(cond)                                                         \
  if (cond) { asm volatile("s_waitcnt vmcnt(%0)" :: "n"(LPT) : "memory"); }    \
  else      { asm volatile("s_waitcnt vmcnt(0)" ::: "memory"); }               \
  __builtin_amdgcn_s_barrier();                                                \
  __builtin_amdgcn_sched_barrier(0);

  const int NT = K >> 5;
  stageAB(slA[0], slB[0]);
  stageAB(slA[1], slB[1]);
  stageAB(slA[2], slB[2]);
  // retire slots 0,1 (keep slot 2 in flight); make visible
  asm volatile("s_waitcnt vmcnt(%0)" :: "n"(LPT) : "memory");
  __builtin_amdgcn_s_barrier();
  __builtin_amdgcn_sched_barrier(0);

  bf16x8 fa0[RB], fb0[4], fa1[RB], fb1[4];
  rdFrags(slA[0], slB[0], fa0, fb0);

  for (int t = 0; t < NT; t += 4) {
    // ---- tile t (slot 0, regs fa0) ----
    if (t + 1 < NT) rdFrags(slA[1], slB[1], fa1, fb1);
    if (t + 3 < NT) stageAB(slA[3], slB[3]);
    doMFMA(fa0, fb0);
    BOUNDARY(t + 3 < NT)
    // ---- tile t+1 (slot 1, regs fa1) ----
    if (t + 1 < NT) {
      if (t + 2 < NT) rdFrags(slA[2], slB[2], fa0, fb0);
      if (t + 4 < NT) stageAB(slA[0], slB[0]);
      doMFMA(fa1, fb1);
      BOUNDARY(t + 4 < NT)
    }
    // ---- tile t+2 (slot 2, regs fa0) ----
    if (t + 2 < NT) {
      if (t + 3 < NT) rdFrags(slA[3], slB[3], fa1, fb1);
      if (t + 5 < NT) stageAB(slA[1], slB[1]);
      doMFMA(fa0, fb0);
      BOUNDARY(t + 5 < NT)
    }
    // ---- tile t+3 (slot 3, regs fa1) ----
    if (t + 3 < NT) {
      if (t + 4 < NT) rdFrags(slA[0], slB[0], fa0, fb0);
      if (t + 6 < NT) stageAB(slA[2], slB[2]);
      doMFMA(fa1, fb1);
      BOUNDARY(t + 6 < NT)
    }
  }
#undef BOUNDARY

  // ---- epilogue ----  C/D: row=(lane>>4)*4+reg, col=lane&15
  const int er = (lane >> 4) * 4, ec = lane & 15;
  const int bmb = bm * BM + wrow, bnb = bn * 256 + wcol;
  if constexpr (EPI == 6) {
#pragma unroll
    for (int m = 0; m < RB; ++m)
#pragma unroll
      for (int rr = 0; rr < 4; ++rr) {
        const size_t grow = bmb + m * 16 + er + rr;
#pragma unroll
        for (int n = 0; n < 4; n += 2) {
          const int oc = ((bnb + n * 16) >> 5) * 16 + ec;
          const float g = acc[m][n][rr], u = acc[m][n + 1][rr];
          const float sg = 1.f / (1.f + __expf(-g));
          Cb[grow * DFF + oc] = f2b(u * g * sg);
        }
      }
  } else {
#pragma unroll
    for (int m = 0; m < RB; ++m)
#pragma unroll
      for (int rr = 0; rr < 4; ++rr) {
        const int grow = bmb + m * 16 + er + rr;
#pragma unroll
        for (int n = 0; n < 4; ++n) {
          const int gcol = bnb + n * 16 + ec;
          if (gcol < Nbound) {
            const float v = acc[m][n][rr];
            if constexpr (EPI == 1) {
              const size_t idx = (size_t)grow * ldC + gcol;
              Cf[idx] = v + auxf[idx];
            } else if constexpr (EPI == 4) {
              Cb[(size_t)grow * ldC + gcol] = f2b(v);
            } else if constexpr (EPI == 5) {
              Fdt[(size_t)grow * NH + gcol] = v;
            }
          }
        }
      }
  }
}

// ---------------------------------------------------------------------------
__global__ void cvt_kernel(const float* __restrict__ s, u16* __restrict__ d, int n4) {
  const int i = blockIdx.x * 256 + threadIdx.x;
  if (i >= n4) return;
  const float4 v = ((const float4*)s)[i];
  ushort4 r;
  r.x = f2b(v.x); r.y = f2b(v.y); r.z = f2b(v.z); r.w = f2b(v.w);
  ((ushort4*)d)[i] = r;
}

// gate/up weights -> bf16, 16-row interleaved: virtual rows [g*32, g*32+16) =
// gate rows [g*16, g*16+16), [g*32+16, g*32+32) = up rows (for fused EPI 6).
__global__ void cvt_gateup_kernel(const float* __restrict__ g, const float* __restrict__ u,
                                  u16* __restrict__ d) {
  const int i = blockIdx.x * 256 + threadIdx.x;
  const int total = 2 * DFF * D_MODEL / 4;
  if (i >= total) return;
  const int rowlen4 = D_MODEL / 4;
  const int vrow = i / rowlen4, c4 = i % rowlen4;
  const bool isg = vrow < DFF;
  const int sr = isg ? vrow : vrow - DFF;
  const float4 v = ((const float4*)(isg ? g : u))[(size_t)sr * rowlen4 + c4];
  const int dr = (sr >> 4) * 32 + (isg ? 0 : 16) + (sr & 15);
  ushort4 rr; rr.x = f2b(v.x); rr.y = f2b(v.y); rr.z = f2b(v.z); rr.w = f2b(v.w);
  ((ushort4*)d)[(size_t)dr * rowlen4 + c4] = rr;
}

__global__ void rmsnorm_kernel(const float* __restrict__ x, const float* __restrict__ w,
                               u16* __restrict__ o) {
  const int row = blockIdx.x;
  const float* xr = x + (size_t)row * D_MODEL;
  float ss = 0.f;
  for (int c = threadIdx.x; c < D_MODEL; c += 256) { const float v = xr[c]; ss += v * v; }
#pragma unroll
  for (int off = 32; off > 0; off >>= 1) ss += __shfl_down(ss, off, 64);
  __shared__ float red[4];
  if ((threadIdx.x & 63) == 0) red[threadIdx.x >> 6] = ss;
  __syncthreads();
  const float scale = rsqrtf((red[0] + red[1] + red[2] + red[3]) * (1.f / D_MODEL) + 1e-5f);
  u16* orow = o + (size_t)row * D_MODEL;
  for (int c = threadIdx.x; c < D_MODEL; c += 256) orow[c] = f2b(xr[c] * scale * w[c]);
}

// causal depthwise conv over seq dim; reads xBC slice of bf16 zxbcdt.
__global__ void conv_kernel(const u16* __restrict__ zx, const float* __restrict__ cw,
                            const float* __restrict__ cb, u16* __restrict__ out) {
  const int idx = blockIdx.x * 256 + threadIdx.x;   // M_TOK * CONV_DIM
  const int ch = idx % CONV_DIM;
  const int m = idx / CONV_DIM;
  const int l = m & (SEQ - 1);
  float accv = cb[ch];
#pragma unroll
  for (int k = 0; k < 4; ++k) {
    const int ls = l - 3 + k;
    if (ls >= 0) accv += cw[ch * 4 + k] * b2f(zx[(size_t)(m - 3 + k) * D_IN_PROJ + D_INNER + ch]);
  }
  out[idx] = f2b(accv);
}

// per (b,chunk,head): cum[i] = sum_{i'<=i} -softplus(dt)   (dt fp32 side buf)
__global__ void dtcum_kernel(const float* __restrict__ dtbuf, float* __restrict__ cum) {
  const int blk = blockIdx.x;                       // b*512 + c*32 + h
  const int h = blk & 31, cc = (blk >> 5) & 15, b = blk >> 9;
  const int i = threadIdx.x;                        // 0..127
  const int m = b * SEQ + cc * CHUNK + i;
  const float dt = dtbuf[(size_t)m * NH + h];
  const float sp = (dt > 20.f) ? dt : log1pf(__expf(dt));
  __shared__ float s[128];
  s[i] = -sp;
  __syncthreads();
  for (int off = 1; off < 128; off <<= 1) {
    const float v = (i >= off) ? s[i - off] : 0.f;
    __syncthreads();
    s[i] += v;
    __syncthreads();
  }
  cum[(size_t)m * NH + h] = s[i];
}

// per (b,chunk,head): S[n][p] = sum_q exp(cum_last - cum_q) * B[q][n] * x[q][p]
__global__ void state_kernel(const u16* __restrict__ xbc, const float* __restrict__ cum,
                             float* __restrict__ S) {
  const int blk = blockIdx.x;
  const int h = blk & 31, cc = (blk >> 5) & 15, b = blk >> 9;
  const int m0 = b * SEQ + cc * CHUNK;
  const int tid = threadIdx.x;
  const int tp = tid & 63, tg = tid >> 6;
  const int n0 = tg * 16;
  const float cl = cum[(size_t)(m0 + 127) * NH + h];
  __shared__ float sBq[32][64], sxq[32][64], sd[32];
  float accv[16];
#pragma unroll
  for (int i = 0; i < 16; ++i) accv[i] = 0.f;
  for (int q0 = 0; q0 < 128; q0 += 32) {
    __syncthreads();
    for (int e = tid; e < 2048; e += 256) {
      const int q = e >> 6, col = e & 63;
      const size_t rowb = (size_t)(m0 + q0 + q) * CONV_DIM;
      sBq[q][col] = b2f(xbc[rowb + D_INNER + h * 64 + col]);
      sxq[q][col] = b2f(xbc[rowb + h * 64 + col]);
    }
    if (tid < 32) sd[tid] = __expf(cl - cum[(size_t)(m0 + q0 + tid) * NH + h]);
    __syncthreads();
    for (int q = 0; q < 32; ++q) {
      const float xv = sxq[q][tp] * sd[q];
#pragma unroll
      for (int i = 0; i < 16; ++i) accv[i] += sBq[q][n0 + i] * xv;
    }
  }
  float* Sp = S + (((size_t)(b * 16 + cc) * NH + h) * 64) * 64;
#pragma unroll
  for (int i = 0; i < 16; ++i) Sp[(size_t)(n0 + i) * 64 + tp] = accv[i];
}

// inter-chunk scan: Hprev[c] = state before chunk c (16 sequential steps)
__global__ void scan_kernel(const float* __restrict__ S, const float* __restrict__ cum,
                            float* __restrict__ H) {
  const int idx = blockIdx.x * 256 + threadIdx.x;   // BATCH*NH*64*64
  const int p = idx & 63, n = (idx >> 6) & 63, h = (idx >> 12) & 31, b = idx >> 17;
  float hs = 0.f;
  for (int cc = 0; cc < NCHUNK; ++cc) {
    const size_t off = (((size_t)(b * 16 + cc) * NH + h) * 64 + n) * 64 + p;
    H[off] = hs;
    const float Ac = __expf(cum[(size_t)(b * SEQ + cc * CHUNK + 127) * NH + h]);
    hs = Ac * hs + S[off];
  }
}

// ---------------------------------------------------------------------------
// y_kernel (MFMA): one block per (b, chunk, head).
// Phase 1: P = mask(exp(cum_i-cum_j) * C·B^T)  [MFMA, bf16 P in LDS]
// Phase 2: Y = P·x + (exp(cum)·C)·H            [MFMA], then +D*x, z-silu gate.
// LDS strides padded (+8 u16) -> 2-way bank aliasing only (free).
// ---------------------------------------------------------------------------
#define SPITCH 136   // sP / sxT row pitch (u16)
#define CPITCH 72    // sC / sB / sHT row pitch (u16)
__global__ void __launch_bounds__(256, 2) y_kernel(
    const u16* __restrict__ xbc, const float* __restrict__ cum,
    const float* __restrict__ H, const float* __restrict__ Dp,
    const u16* __restrict__ zx, const float* __restrict__ zb,
    u16* __restrict__ yo) {
  const int blk = blockIdx.x;            // b*512 + cc*32 + h
  const int h = blk & 31, cc = (blk >> 5) & 15, b = blk >> 9;
  const int m0 = b * SEQ + cc * CHUNK;
  const int tid = threadIdx.x;
  const int lane = tid & 63, wave = tid >> 6;

  __shared__ __align__(16) u16 sC[128 * CPITCH];          // 18 KB  C[i][n] (later exp-scaled)
  __shared__ __align__(16) u16 sU[64 * SPITCH + 64 * CPITCH]; // 26 KB  ph1: sB[j][n]; ph2: sxT[p][j] + sHT[p][n]
  __shared__ __align__(16) u16 sP[128 * SPITCH];          // 34 KB  P[i][j] bf16
  __shared__ float sCum[128];
  u16* sB = sU;
  u16* sxT = sU;
  u16* sHT = sU + 64 * SPITCH;

  // ---- load C, B, cum ----
  {
    const int i = tid >> 4, n4 = (tid & 15) * 4;          // 8 rows/iter, ushort4
    for (int i0 = 0; i0 < 128; i0 += 16) {
      const size_t g = (size_t)(m0 + i0 + i) * CONV_DIM + h * 64 + n4;
      *(ushort4*)&sC[(i0 + i) * CPITCH + n4] = *(const ushort4*)&xbc[g + 2 * D_INNER];
      *(ushort4*)&sB[(i0 + i) * CPITCH + n4] = *(const ushort4*)&xbc[g + D_INNER];
    }
    if (tid < 128) sCum[tid] = cum[(size_t)(m0 + tid) * NH + h];
  }
  __syncthreads();

  const int lr = lane & 15;
  const int lk = (lane >> 4) * 8;
  const int er = (lane >> 4) * 4;
  const int ec = lane & 15;

  // ---- phase 1: scores ----
  {
    const int R = (wave >> 1) * 64, Cq = (wave & 1) * 64;
    const f32x4 z4 = {0.f, 0.f, 0.f, 0.f};
    f32x4 acc[4][4];
#pragma unroll
    for (int i = 0; i < 4; ++i)
#pragma unroll
      for (int j = 0; j < 4; ++j) acc[i][j] = z4;
#pragma unroll
    for (int k0 = 0; k0 < 64; k0 += 32) {
      bf16x8 af[4], bfv[4];
#pragma unroll
      for (int mi = 0; mi < 4; ++mi)
        af[mi] = *(const bf16x8*)&sC[(R + mi * 16 + lr) * CPITCH + k0 + lk];
#pragma unroll
      for (int ni = 0; ni < 4; ++ni)
        bfv[ni] = *(const bf16x8*)&sB[(Cq + ni * 16 + lr) * CPITCH + k0 + lk];
#pragma unroll
      for (int mi = 0; mi < 4; ++mi)
#pragma unroll
        for (int ni = 0; ni < 4; ++ni)
          acc[mi][ni] = __builtin_amdgcn_mfma_f32_16x16x32_bf16(af[mi], bfv[ni], acc[mi][ni], 0, 0, 0);
    }
#pragma unroll
    for (int mi = 0; mi < 4; ++mi)
#pragma unroll
      for (int r = 0; r < 4; ++r) {
        const int row = R + mi * 16 + er + r;
#pragma unroll
        for (int ni = 0; ni < 4; ++ni) {
          const int col = Cq + ni * 16 + ec;
          const float pv = (row >= col) ? __expf(sCum[row] - sCum[col]) * acc[mi][ni][r] : 0.f;
          sP[row * SPITCH + col] = f2b(pv);
        }
      }
  }
  __syncthreads();

  // ---- phase 1.5: scale C rows by exp(cum); load x^T, H^T (overwrite sB) ----
  {
    const int i = tid >> 1, n32 = (tid & 1) * 32;         // sC scale: 128 rows x 64
    const float sc = __expf(sCum[i]);
    for (int n = n32; n < n32 + 32; ++n)
      sC[i * CPITCH + n] = f2b(b2f(sC[i * CPITCH + n]) * sc);
  }
  {
    const int j = tid >> 1, p32 = (tid & 1) * 32;         // x[j][p] -> sxT[p][j]
    const size_t g = (size_t)(m0 + j) * CONV_DIM + h * 64;
    for (int p = p32; p < p32 + 32; ++p)
      sxT[p * SPITCH + j] = xbc[g + p];
    const float* Hp = H + (((size_t)(b * 16 + cc) * NH + h) * 64) * 64;
    if (j < 64) {                                          // H[n][p] -> sHT[p][n]
      const int n = j;
      for (int p = p32; p < p32 + 32; ++p)
        sHT[p * CPITCH + n] = f2b(Hp[n * 64 + p]);
    }
  }
  __syncthreads();

  // ---- phase 2: Y = P·x + Cs·H ----
  {
    const int R2 = wave * 32;
    const f32x4 z4 = {0.f, 0.f, 0.f, 0.f};
    f32x4 acc[2][4];
#pragma unroll
    for (int i = 0; i < 2; ++i)
#pragma unroll
      for (int j = 0; j < 4; ++j) acc[i][j] = z4;
#pragma unroll
    for (int k0 = 0; k0 < 128; k0 += 32) {                 // P·x
      bf16x8 af[2], bfv[4];
#pragma unroll
      for (int mi = 0; mi < 2; ++mi)
        af[mi] = *(const bf16x8*)&sP[(R2 + mi * 16 + lr) * SPITCH + k0 + lk];
#pragma unroll
      for (int ni = 0; ni < 4; ++ni)
        bfv[ni] = *(const bf16x8*)&sxT[(ni * 16 + lr) * SPITCH + k0 + lk];
#pragma unroll
      for (int mi = 0; mi < 2; ++mi)
#pragma unroll
        for (int ni = 0; ni < 4; ++ni)
          acc[mi][ni] = __builtin_amdgcn_mfma_f32_16x16x32_bf16(af[mi], bfv[ni], acc[mi][ni], 0, 0, 0);
    }
#pragma unroll
    for (int k0 = 0; k0 < 64; k0 += 32) {                  // Cs·H
      bf16x8 af[2], bfv[4];
#pragma unroll
      for (int mi = 0; mi < 2; ++mi)
        af[mi] = *(const bf16x8*)&sC[(R2 + mi * 16 + lr) * CPITCH + k0 + lk];
#pragma unroll
      for (int ni = 0; ni < 4; ++ni)
        bfv[ni] = *(const bf16x8*)&sHT[(ni * 16 + lr) * CPITCH + k0 + lk];
#pragma unroll
      for (int mi = 0; mi < 2; ++mi)
#pragma unroll
        for (int ni = 0; ni < 4; ++ni)
          acc[mi][ni] = __builtin_amdgcn_mfma_f32_16x16x32_bf16(af[mi], bfv[ni], acc[mi][ni], 0, 0, 0);
    }
    // epilogue: += D*x, z-silu gate, bf16 store
    const float Dh = Dp[h];
#pragma unroll
    for (int mi = 0; mi < 2; ++mi)
#pragma unroll
      for (int r = 0; r < 4; ++r) {
        const int row = R2 + mi * 16 + er + r;
        const int m = m0 + row;
#pragma unroll
        for (int ni = 0; ni < 4; ++ni) {
          const int p = ni * 16 + ec;
          const int gc = h * 64 + p;
          const float xv = b2f(sxT[p * SPITCH + row]);
          const float z = b2f(zx[(size_t)m * D_IN_PROJ + gc]) + zb[gc];
          const float sg = 1.f / (1.f + __expf(-z));
          yo[(size_t)m * D_INNER + gc] = f2b((acc[mi][ni][r] + Dh * xv) * z * sg);
        }
      }
  }
}

// ---------------------------------------------------------------------------
extern "C" void kernel_launch(void* const* d_in, const int* in_sizes, int n_in,
                              void* d_out, int out_size, void* d_ws, size_t ws_size,
                              hipStream_t stream) {
  (void)in_sizes; (void)n_in; (void)out_size; (void)ws_size;
  const float* hidden = (const float*)d_in[0];
  const float* w_in   = (const float*)d_in[1];
  const float* z_bias = (const float*)d_in[2];
  const float* conv_w = (const float*)d_in[3];
  const float* conv_b = (const float*)d_in[4];
  const float* Dp     = (const float*)d_in[5];
  const float* w_out  = (const float*)d_in[6];
  const float* n1w    = (const float*)d_in[7];
  const float* n2w    = (const float*)d_in[8];
  const float* w_g    = (const float*)d_in[9];
  const float* w_u    = (const float*)d_in[10];
  const float* w_d    = (const float*)d_in[11];
  float* out = (float*)d_out;

  // ---- workspace layout (~193.4 MiB total) ----
  char* p = (char*)d_ws;
  auto take = [&](size_t bytes) { char* r = p; p += (bytes + 255) & ~(size_t)255; return r; };
  u16*   Bzx  = (u16*)take((size_t)M_TOK * D_IN_PROJ * 2);              // 64.25 MiB
  u16*   Bxbc = (u16*)take((size_t)M_TOK * CONV_DIM * 2);               // 48 MiB
  float* F_cum = (float*)take((size_t)M_TOK * NH * 4);                  // 0.5 MiB
  float* F_S   = (float*)take((size_t)BATCH * NCHUNK * NH * 64 * 64 * 4); // 16 MiB
  float* F_H   = (float*)take((size_t)BATCH * NCHUNK * NH * 64 * 64 * 4); // 16 MiB
  u16*   B_h   = (u16*)take((size_t)M_TOK * D_MODEL * 2);               // 16 MiB
  float* F_dt  = (float*)take((size_t)M_TOK * NH * 4);                  // 0.5 MiB
  u16*   W_buf = (u16*)take((size_t)D_IN_PROJ * D_MODEL * 2);           // 32.125 MiB
  // overlays (liveness-checked):
  u16* B_y  = (u16*)F_S;    // y-gated output (16 MiB): F_S dead after scan_kernel
  u16* W_gu = Bzx;          // fused gate/up weights (64 MiB): Bzx dead after y_kernel
  u16* B_gu = Bxbc;         // gated-up out (64 MiB): spans Bxbc+F_cum+F_S, all dead
                            // by then (out_proj consumed B_y before gate-up runs)

  const int c2 = (D_MODEL * D_INNER / 4 + 255) / 256;
  const int c8 = (DFF * D_MODEL / 4 + 255) / 256;

  // 1. in_proj: convert weight, norm, main GEMM (N=8192 exact) + dt GEMM (N=32)
  cvt_kernel<<<(D_IN_PROJ * D_MODEL / 4 + 255) / 256, 256, 0, stream>>>(w_in, W_buf, D_IN_PROJ * D_MODEL / 4);
  rmsnorm_kernel<<<M_TOK, 256, 0, stream>>>(hidden, n1w, B_h);
  gemm8<4, 256><<<16 * 32, 512, 0, stream>>>(B_h, W_buf, nullptr, Bzx, nullptr, nullptr,
                                             D_MODEL, 8192, D_IN_PROJ, 32, 8192);
  gemm8<5, 128><<<32, 512, 0, stream>>>(B_h, W_buf + (size_t)8192 * D_MODEL, nullptr, nullptr,
                                        nullptr, F_dt, D_MODEL, NH, 0, 1, 32);

  // 2. conv + SSD scan
  conv_kernel<<<M_TOK * CONV_DIM / 256, 256, 0, stream>>>(Bzx, conv_w, conv_b, Bxbc);
  dtcum_kernel<<<BATCH * NCHUNK * NH, 128, 0, stream>>>(F_dt, F_cum);
  state_kernel<<<BATCH * NCHUNK * NH, 256, 0, stream>>>(Bxbc, F_cum, F_S);
  scan_kernel<<<BATCH * NH * 64 * 64 / 256, 256, 0, stream>>>(F_S, F_cum, F_H);
  y_kernel<<<BATCH * NCHUNK * NH, 256, 0, stream>>>(Bxbc, F_cum, F_H, Dp, Bzx, z_bias, B_y);

  // 3. out_proj (+residual) -> d_out
  cvt_kernel<<<c2, 256, 0, stream>>>(w_out, W_buf, D_MODEL * D_INNER / 4);
  gemm8<1, 128><<<32 * 8, 512, 0, stream>>>(B_y, W_buf, out, nullptr, hidden, nullptr,
                                            D_INNER, D_MODEL, D_MODEL, 8, 2048);

  // 4. MLP: norm2, fused gate-up GEMM (N=16384, interleaved W), down (+residual)
  rmsnorm_kernel<<<M_TOK, 256, 0, stream>>>(out, n2w, B_h);
  cvt_gateup_kernel<<<2 * DFF * D_MODEL / 4 / 256, 256, 0, stream>>>(w_g, w_u, W_gu);
  gemm8<6, 256><<<16 * 64, 512, 0, stream>>>(B_h, W_gu, nullptr, B_gu, nullptr, nullptr,
                                             D_MODEL, 2 * DFF, 0, 64, 16384);
  cvt_kernel<<<c8, 256, 0, stream>>>(w_d, W_buf, D_MODEL * DFF / 4);
  gemm8<1, 128><<<32 * 8, 512, 0, stream>>>(B_gu, W_buf, out, nullptr, out,
                                            nullptr, DFF, D_MODEL, D_MODEL, 8, 2048);
}